// Round 6
// baseline (122.274 us; speedup 1.0000x reference)
//
#include <hip/hip_runtime.h>

#define Bsz 4
#define Nn  256
#define OBSD 40
#define ACTD 8
#define HEADS 8
#define DIMD 32
#define Td  256

#define FMA4(accr, s, wv) \
    (accr).x = fmaf((s), (wv).x, (accr).x); \
    (accr).y = fmaf((s), (wv).y, (accr).y); \
    (accr).z = fmaf((s), (wv).z, (accr).z); \
    (accr).w = fmaf((s), (wv).w, (accr).w)

// K1: emb = relu(relu(obs @ We1 + be1) @ We2 + be2), 2 rows per block.
// grid = B*N/2 = 512 blocks (2 blocks/CU), 256 threads.
// Blocks 0/1 also zero snh/shid (consumed by k_colsum's atomics).
__global__ void k_emb(const float* __restrict__ x,
                      const float* __restrict__ We1, const float* __restrict__ be1,
                      const float* __restrict__ We2, const float* __restrict__ be2,
                      float* __restrict__ emb,
                      float* __restrict__ snh, float* __restrict__ shid) {
    int g = blockIdx.x;
    int t = threadIdx.x;
    int row0 = g * 2;                  // rows row0, row0+1 (never crosses batch)
    int b = row0 >> 8;
    int n0 = row0 & 255;
    if (g == 0)      { for (int i = t; i < Bsz * Td; i += 256) snh[i]  = 0.f; }
    else if (g == 1) { for (int i = t; i < Bsz * Td; i += 256) shid[i] = 0.f; }

    __shared__ float2 obs_t[OBSD];     // obs_t[k] = the 2 rows at obs-channel k
    __shared__ float2 h1_t[Td];        // h1_t[k]  = hidden1 of the 2 rows at channel k
    __shared__ float4 part[4][2][64];  // [wave][row][colgroup] partials (8 KB)
    if (t < 2 * OBSD) {
        int r = t & 1, k = t >> 1;
        ((float*)&obs_t[k])[r] = x[(b * (Nn + 1) + n0 + r) * OBSD + k];
    }
    __syncthreads();

    // Layer 1 (K=40): thread t owns column t for both rows.
    float bias1 = be1[t];
    float a10 = bias1, a11 = bias1;
#pragma unroll
    for (int k = 0; k < OBSD; ++k) {
        float w = We1[k * Td + t];
        float2 ov = obs_t[k];
        a10 = fmaf(ov.x, w, a10);
        a11 = fmaf(ov.y, w, a11);
    }
    h1_t[t] = make_float2(fmaxf(a10, 0.f), fmaxf(a11, 0.f));
    __syncthreads();

    // Layer 2: wave wv handles k in [64wv, 64wv+64); lane c owns cols 4c..4c+3.
    int wv = t >> 6, c = t & 63;
    float4 a2[2] = {};
#pragma unroll 8
    for (int i = 0; i < 64; ++i) {
        int k = (wv << 6) + i;
        float4 wvv = *(const float4*)(We2 + k * Td + 4 * c);
        float2 hv = h1_t[k];
        FMA4(a2[0], hv.x, wvv);
        FMA4(a2[1], hv.y, wvv);
    }
    part[wv][0][c] = a2[0];
    part[wv][1][c] = a2[1];
    __syncthreads();

    // Cross-wave reduce: thread t owns column t for both rows.
    int c2 = t >> 2, j = t & 3;
#pragma unroll
    for (int r = 0; r < 2; ++r) {
        float v = be2[t];
#pragma unroll
        for (int w2 = 0; w2 < 4; ++w2) v += ((const float*)&part[w2][r][c2])[j];
        emb[(row0 + r) * Td + t] = fmaxf(v, 0.f);
    }
}

// K2a: NE[b,m,:] = sum_n adj[m,n] * emb[b,n,:], 2 m-rows per block.
// grid = (N/2, B) = (128, 4) = 512 blocks, 256 threads.
__global__ void k_ne(const float* __restrict__ adj, const float* __restrict__ emb,
                     float* __restrict__ NE) {
    int g = blockIdx.x, b = blockIdx.y;
    int t = threadIdx.x;
    int m0 = g * 2;
    __shared__ float2 arow_t[Nn];      // arow_t[n] = adj rows m0,m0+1 at col n
    __shared__ float4 part[4][2][64];  // 8 KB
    arow_t[t] = make_float2(adj[(m0 + 0) * Nn + t], adj[(m0 + 1) * Nn + t]);
    __syncthreads();

    int wv = t >> 6, c = t & 63;
    const float* eb = emb + b * Nn * Td;
    float4 aN[2] = {};
#pragma unroll 8
    for (int i = 0; i < 64; ++i) {
        int n = (wv << 6) + i;
        float4 ev = *(const float4*)(eb + n * Td + 4 * c);
        float2 ar = arow_t[n];
        FMA4(aN[0], ar.x, ev);
        FMA4(aN[1], ar.y, ev);
    }
    part[wv][0][c] = aN[0];
    part[wv][1][c] = aN[1];
    __syncthreads();

    int c2 = t >> 2, j = t & 3;
#pragma unroll
    for (int r = 0; r < 2; ++r) {
        float v = 0.f;
#pragma unroll
        for (int w2 = 0; w2 < 4; ++w2) v += ((const float*)&part[w2][r][c2])[j];
        NE[(b * Nn + m0 + r) * Td + t] = v;
    }
}

// K2b: snh[b,t] += sum_{j in chunk} relu(NE[b,j]@Wn + bn)[t]; same for shid/Wh.
// 4 j-rows per block. grid = (N/4, B) = (64, 4) = 256 blocks, 256 threads.
__global__ void k_colsum(const float* __restrict__ NE,
                         const float* __restrict__ Wn, const float* __restrict__ bn,
                         const float* __restrict__ Wh, const float* __restrict__ bh,
                         float* __restrict__ snh, float* __restrict__ shid) {
    int g = blockIdx.x, b = blockIdx.y;
    int t = threadIdx.x;
    int j0 = g * 4;
    __shared__ float4 ne4[Td];         // ne4[k] = NE rows j0..j0+3 at channel k
    __shared__ float4 partN[4][4][64]; // 16 KB
    __shared__ float4 partH[4][4][64]; // 16 KB
#pragma unroll
    for (int r = 0; r < 4; ++r)
        ((float*)&ne4[t])[r] = NE[(b * Nn + j0 + r) * Td + t];
    __syncthreads();

    int wv = t >> 6, c = t & 63;
    float4 sN[4] = {};
    float4 sH[4] = {};
#pragma unroll 8
    for (int i = 0; i < 64; ++i) {
        int k = (wv << 6) + i;
        float4 nv = ne4[k];            // ds_read_b128 broadcast
        float4 wn4 = *(const float4*)(Wn + k * Td + 4 * c);
        float4 wh4 = *(const float4*)(Wh + k * Td + 4 * c);
        FMA4(sN[0], nv.x, wn4);  FMA4(sH[0], nv.x, wh4);
        FMA4(sN[1], nv.y, wn4);  FMA4(sH[1], nv.y, wh4);
        FMA4(sN[2], nv.z, wn4);  FMA4(sH[2], nv.z, wh4);
        FMA4(sN[3], nv.w, wn4);  FMA4(sH[3], nv.w, wh4);
    }
#pragma unroll
    for (int r = 0; r < 4; ++r) { partN[wv][r][c] = sN[r]; partH[wv][r][c] = sH[r]; }
    __syncthreads();

    // Reduce over waves (pre-relu!), add bias, relu, sum the 4 j-rows, atomic.
    int c2 = t >> 2, j = t & 3;
    float bnt = bn[t], bht = bh[t];
    float rs1 = 0.f, rs2 = 0.f;
#pragma unroll
    for (int r = 0; r < 4; ++r) {
        float v1 = bnt, v2 = bht;
#pragma unroll
        for (int w2 = 0; w2 < 4; ++w2) {
            v1 += ((const float*)&partN[w2][r][c2])[j];
            v2 += ((const float*)&partH[w2][r][c2])[j];
        }
        rs1 += fmaxf(v1, 0.f);
        rs2 += fmaxf(v2, 0.f);
    }
    atomicAdd(&snh[b * Td + t], rs1);
    atomicAdd(&shid[b * Td + t], rs2);
}

// K3: per-batch target row -> ah -> softmax over DIM per head -> mean -> Wa
__global__ void k_final(const float* __restrict__ x, const float* __restrict__ emb,
                        const float* __restrict__ Wl, const float* __restrict__ bl,
                        const float* __restrict__ snh, const float* __restrict__ shid,
                        const float* __restrict__ Wa, const float* __restrict__ ba,
                        float* __restrict__ out) {
    int b = blockIdx.x;
    int t = threadIdx.x;
    int tgt = (int)x[(b * (Nn + 1) + Nn) * OBSD + 0];
    tgt = tgt < 0 ? 0 : (tgt > Nn - 1 ? Nn - 1 : tgt);
    __shared__ float erow[Td], lg[Td], p[Td], od[DIMD];
    __shared__ float4 partL[4][64];
    erow[t] = emb[(b * Nn + tgt) * Td + t];
    __syncthreads();

    int wv = t >> 6, c = t & 63;
    float4 aL = {};
#pragma unroll 8
    for (int i = 0; i < 64; ++i) {
        int k = (wv << 6) + i;
        float4 wlv = *(const float4*)(Wl + k * Td + 4 * c);
        FMA4(aL, erow[k], wlv);
    }
    partL[wv][c] = aL;
    __syncthreads();

    int c2 = t >> 2, j = t & 3;
    float acc = bl[t];
#pragma unroll
    for (int w2 = 0; w2 < 4; ++w2) acc += ((const float*)&partL[w2][c2])[j];
    float ah = fmaxf(acc, 0.f);
    lg[t] = ah * snh[b * Td + t];   // logit for (d = t>>3, h = t&7)
    __syncthreads();
    int h = t & 7;
    float mx = -1e30f;
#pragma unroll
    for (int d = 0; d < DIMD; ++d) mx = fmaxf(mx, lg[d * HEADS + h]);
    float se = 0.f;
#pragma unroll
    for (int d = 0; d < DIMD; ++d) se += __expf(lg[d * HEADS + h] - mx);
    float attn = __expf(lg[t] - mx) / se;
    p[t] = attn * shid[b * Td + t];
    __syncthreads();
    if (t < DIMD) {
        float s = 0.f;
#pragma unroll
        for (int hh = 0; hh < HEADS; ++hh) s += p[t * HEADS + hh];
        od[t] = s * (1.f / HEADS);
    }
    __syncthreads();
    if (t < ACTD) {
        float s = ba[t];
#pragma unroll
        for (int d = 0; d < DIMD; ++d) s = fmaf(od[d], Wa[d * ACTD + t], s);
        out[b * ACTD + t] = s;
    }
}

extern "C" void kernel_launch(void* const* d_in, const int* in_sizes, int n_in,
                              void* d_out, int out_size, void* d_ws, size_t ws_size,
                              hipStream_t stream) {
    const float* x   = (const float*)d_in[0];
    const float* adj = (const float*)d_in[1];
    const float* We1 = (const float*)d_in[2];
    const float* be1 = (const float*)d_in[3];
    const float* We2 = (const float*)d_in[4];
    const float* be2 = (const float*)d_in[5];
    const float* Wl  = (const float*)d_in[6];
    const float* bl  = (const float*)d_in[7];
    const float* Wn  = (const float*)d_in[8];
    const float* bn  = (const float*)d_in[9];
    const float* Wh  = (const float*)d_in[10];
    const float* bh  = (const float*)d_in[11];
    const float* Wa  = (const float*)d_in[12];
    const float* ba  = (const float*)d_in[13];
    float* out = (float*)d_out;

    // ws layout: emb f32[B*N*T] (1 MB) | NE f32[B*N*T] (1 MB) | snh | shid
    float* emb  = (float*)d_ws;
    float* NE   = emb + Bsz * Nn * Td;
    float* snh  = NE + Bsz * Nn * Td;
    float* shid = snh + Bsz * Td;

    k_emb<<<dim3(Bsz * Nn / 2), dim3(Td), 0, stream>>>(x, We1, be1, We2, be2, emb, snh, shid);
    k_ne<<<dim3(Nn / 2, Bsz), dim3(Td), 0, stream>>>(adj, emb, NE);
    k_colsum<<<dim3(Nn / 4, Bsz), dim3(Td), 0, stream>>>(NE, Wn, bn, Wh, bh, snh, shid);
    k_final<<<dim3(Bsz), dim3(Td), 0, stream>>>(x, emb, Wl, bl, snh, shid, Wa, ba, out);
}